// Round 3
// baseline (96.438 us; speedup 1.0000x reference)
//
#include <hip/hip_runtime.h>

// Problem constants (from reference setup_inputs)
constexpr int Bn = 16;
constexpr int Hn = 512;
constexpr int Wn = 512;
constexpr int PADR = 15;              // 31x31 window, pad 15
constexpr float INV_KK = 1.0f / (31.0f * 31.0f);
constexpr int HCH = 8;                // rows per block in vbox kernel

// ---------------- pass 1: vertical 31-tap box sum of mask_f ---------------
// grid (Hn/HCH, Bn), 256 thr; thread owns 2 adjacent columns (int2/float2).
// Also zeroes the accumulator (block 0,0) -- ordering safe across launches.
__global__ void vbox_kernel(const int* __restrict__ mask,
                            float* __restrict__ vsum,
                            float* __restrict__ acc) {
    if (blockIdx.x == 0 && blockIdx.y == 0 && threadIdx.x < 4 * Bn)
        acc[threadIdx.x] = 0.0f;

    const int h0 = blockIdx.x * HCH;
    const int b = blockIdx.y;
    const int w2 = threadIdx.x * 2;                     // column pair base

    const int* mb = mask + (size_t)b * Hn * Wn;
    float* vb = vsum + (size_t)b * Hn * Wn;

    // build initial vertical window for h = h0: rows [h0-15, h0+15] clipped
    float sx = 0.0f, sy = 0.0f;
    const int lo = (h0 - PADR < 0) ? 0 : h0 - PADR;
    const int hi = (h0 + PADR > Hn - 1) ? Hn - 1 : h0 + PADR;
    for (int j = lo; j <= hi; ++j) {
        const int2 mm = *reinterpret_cast<const int2*>(mb + j * Wn + w2);
        sx += (mm.x == 255) ? 0.0f : (float)mm.x;
        sy += (mm.y == 255) ? 0.0f : (float)mm.y;
    }

#pragma unroll
    for (int h = h0; h < h0 + HCH; ++h) {
        *reinterpret_cast<float2*>(vb + h * Wn + w2) = make_float2(sx, sy);
        const int ha = h + PADR + 1;                    // row entering window
        const int hs_ = h - PADR;                       // row leaving window
        if (ha < Hn) {
            const int2 mm = *reinterpret_cast<const int2*>(mb + ha * Wn + w2);
            sx += (mm.x == 255) ? 0.0f : (float)mm.x;
            sy += (mm.y == 255) ? 0.0f : (float)mm.y;
        }
        if (hs_ >= 0) {
            const int2 mm = *reinterpret_cast<const int2*>(mb + hs_ * Wn + w2);
            sx -= (mm.x == 255) ? 0.0f : (float)mm.x;
            sy -= (mm.y == 255) ? 0.0f : (float)mm.y;
        }
    }
}

// ------- pass 2: horizontal box via row prefix scan + full loss math ------
// grid (Hn, Bn): one block per image row. 256 thr, 2 elems/thread.
__global__ void fused_kernel(const float* __restrict__ pred,
                             const int* __restrict__ mask,
                             const float* __restrict__ vsum,
                             float* __restrict__ acc) {
    const int h = blockIdx.x;
    const int b = blockIdx.y;
    const int t = threadIdx.x;
    const int lane = t & 63;
    const int wv = t >> 6;

    const float* vrow = vsum + ((size_t)b * Hn + h) * Wn;
    const int* mrow = mask + ((size_t)b * Hn + h) * Wn;
    const float* p0r = pred + ((size_t)b * 2 * Hn + h) * Wn;
    const float* p1r = p0r + (size_t)Hn * Wn;

    __shared__ float P[Wn];                    // inclusive prefix of vsum row
    __shared__ float wtot[4];
    __shared__ float red[4][4];

    // ---- inclusive prefix scan of the vsum row (pair-per-thread) ----
    const float2 vv = *reinterpret_cast<const float2*>(vrow + 2 * t);
    float x = vv.x + vv.y;                     // pair sum
    const float pairSum = x;
#pragma unroll
    for (int off = 1; off < 64; off <<= 1) {
        const float n = __shfl_up(x, off, 64);
        if (lane >= off) x += n;
    }
    if (lane == 63) wtot[wv] = x;
    __syncthreads();
    float woff = 0.0f;
#pragma unroll
    for (int k = 0; k < 4; ++k) woff += (k < wv) ? wtot[k] : 0.0f;
    const float pre = woff + (x - pairSum);    // exclusive prefix of pairs
    P[2 * t] = pre + vv.x;
    P[2 * t + 1] = pre + vv.x + vv.y;
    __syncthreads();

    // ---- loss math for elements i = 2t, 2t+1 ----
    const int2 mm = *reinterpret_cast<const int2*>(mrow + 2 * t);
    const float2 q0 = *reinterpret_cast<const float2*>(p0r + 2 * t);
    const float2 q1 = *reinterpret_cast<const float2*>(p1r + 2 * t);

    float a_weit = 0.0f, a_wbce = 0.0f, a_inter = 0.0f, a_card = 0.0f;
#pragma unroll
    for (int k = 0; k < 2; ++k) {
        const int i = 2 * t + k;
        int m = k ? mm.y : mm.x;
        if (m == 255) m = 0;
        const float mf = (float)m;
        const float p0 = k ? q0.y : q0.x;
        const float p1 = k ? q1.y : q1.x;

        const int ihi = (i + PADR > Wn - 1) ? Wn - 1 : i + PADR;
        const float plo = (i >= PADR + 1) ? P[i - PADR - 1] : 0.0f;
        const float pooled = (P[ihi] - plo) * INV_KK;

        // stable 2-class log-softmax
        const float mx = fmaxf(p0, p1);
        const float lse = mx + __logf(__expf(p0 - mx) + __expf(p1 - mx));
        const float lp0 = p0 - lse;
        const float lp1 = p1 - lse;

        const float wbce = m ? -lp1 : -lp0;
        const float p1s = __expf(lp1);

        const float weit = 1.0f + 5.0f * fabsf(pooled - mf);
        a_weit += weit;
        a_wbce += weit * wbce;
        a_inter += p1s * mf * weit;
        a_card += (p1s + mf) * weit;
    }

    // ---- block reduction: 4 waves of 64 ----
#pragma unroll
    for (int off = 32; off > 0; off >>= 1) {
        a_weit += __shfl_down(a_weit, off, 64);
        a_wbce += __shfl_down(a_wbce, off, 64);
        a_inter += __shfl_down(a_inter, off, 64);
        a_card += __shfl_down(a_card, off, 64);
    }
    if (lane == 0) {
        red[wv][0] = a_weit;
        red[wv][1] = a_wbce;
        red[wv][2] = a_inter;
        red[wv][3] = a_card;
    }
    __syncthreads();
    if (t < 4) {
        const float v = red[0][t] + red[1][t] + red[2][t] + red[3][t];
        atomicAdd(&acc[b * 4 + t], v);
    }
}

// ---------------- finalize: per-batch loss, mean over batch ---------------
__global__ void finalize_kernel(const float* __restrict__ acc, float* __restrict__ out) {
    const int t = threadIdx.x;
    float v = 0.0f;
    if (t < Bn) {
        const float sw = acc[t * 4 + 0];
        const float swb = acc[t * 4 + 1];
        const float inter = acc[t * 4 + 2];
        const float card = acc[t * 4 + 3];
        const float wbce = swb / sw;
        const float uni = card - inter;
        const float wiou = 1.0f - (inter + 1.0f) / (uni + 1.0f);
        v = wbce + wiou;
    }
#pragma unroll
    for (int off = 32; off > 0; off >>= 1) v += __shfl_down(v, off, 64);
    if (t == 0) out[0] = v * (1.0f / (float)Bn);
}

extern "C" void kernel_launch(void* const* d_in, const int* in_sizes, int n_in,
                              void* d_out, int out_size, void* d_ws, size_t ws_size,
                              hipStream_t stream) {
    const float* pred = (const float*)d_in[0];
    const int* mask = (const int*)d_in[1];
    float* vsum = (float*)d_ws;                          // B*H*W floats = 16 MB
    float* acc = vsum + (size_t)Bn * Hn * Wn;            // 4*B floats
    float* out = (float*)d_out;

    hipLaunchKernelGGL(vbox_kernel, dim3(Hn / HCH, Bn), dim3(256), 0, stream,
                       mask, vsum, acc);
    hipLaunchKernelGGL(fused_kernel, dim3(Hn, Bn), dim3(256), 0, stream,
                       pred, mask, vsum, acc);
    hipLaunchKernelGGL(finalize_kernel, dim3(1), dim3(64), 0, stream, acc, out);
}

// Round 4
// 45.096 us; speedup vs baseline: 2.1385x; 2.1385x over previous
//
#include <hip/hip_runtime.h>

// Problem constants (from reference setup_inputs)
constexpr int Bn = 16;
constexpr int Hn = 512;
constexpr int Wn = 512;
constexpr int PADR = 15;              // 31x31 window, pad 15
constexpr float INV_KK = 1.0f / (31.0f * 31.0f);
constexpr int HCH = 8;                // rows per block in vbox kernel

// ---------------- pass 1: vertical 31-tap box sum of mask_f ---------------
// grid (Hn/HCH, Bn), 128 thr; thread owns 4 adjacent columns (int4/float4).
__global__ void vbox_kernel(const int* __restrict__ mask,
                            float* __restrict__ vsum) {
    const int h0 = blockIdx.x * HCH;
    const int b = blockIdx.y;
    const int w4 = threadIdx.x * 4;                     // column quad base

    const int* mb = mask + (size_t)b * Hn * Wn;
    float* vb = vsum + (size_t)b * Hn * Wn;

    float s0 = 0.f, s1 = 0.f, s2 = 0.f, s3 = 0.f;
    const int lo = (h0 - PADR < 0) ? 0 : h0 - PADR;
    const int hi = (h0 + PADR > Hn - 1) ? Hn - 1 : h0 + PADR;
    for (int j = lo; j <= hi; ++j) {
        const int4 mm = *reinterpret_cast<const int4*>(mb + j * Wn + w4);
        s0 += (mm.x == 255) ? 0.0f : (float)mm.x;
        s1 += (mm.y == 255) ? 0.0f : (float)mm.y;
        s2 += (mm.z == 255) ? 0.0f : (float)mm.z;
        s3 += (mm.w == 255) ? 0.0f : (float)mm.w;
    }

#pragma unroll
    for (int h = h0; h < h0 + HCH; ++h) {
        *reinterpret_cast<float4*>(vb + h * Wn + w4) = make_float4(s0, s1, s2, s3);
        const int ha = h + PADR + 1;                    // row entering window
        const int hs_ = h - PADR;                       // row leaving window
        if (ha < Hn) {
            const int4 mm = *reinterpret_cast<const int4*>(mb + ha * Wn + w4);
            s0 += (mm.x == 255) ? 0.0f : (float)mm.x;
            s1 += (mm.y == 255) ? 0.0f : (float)mm.y;
            s2 += (mm.z == 255) ? 0.0f : (float)mm.z;
            s3 += (mm.w == 255) ? 0.0f : (float)mm.w;
        }
        if (hs_ >= 0) {
            const int4 mm = *reinterpret_cast<const int4*>(mb + hs_ * Wn + w4);
            s0 -= (mm.x == 255) ? 0.0f : (float)mm.x;
            s1 -= (mm.y == 255) ? 0.0f : (float)mm.y;
            s2 -= (mm.z == 255) ? 0.0f : (float)mm.z;
            s3 -= (mm.w == 255) ? 0.0f : (float)mm.w;
        }
    }
}

// ------- pass 2: horizontal box via row prefix scan + full loss math ------
// grid (Hn, Bn): one block per image row. 256 thr, 2 elems/thread.
// Writes 4 partials per block to part[b][h][4] -- NO atomics.
__global__ void fused_kernel(const float* __restrict__ pred,
                             const int* __restrict__ mask,
                             const float* __restrict__ vsum,
                             float* __restrict__ part) {
    const int h = blockIdx.x;
    const int b = blockIdx.y;
    const int t = threadIdx.x;
    const int lane = t & 63;
    const int wv = t >> 6;

    const float* vrow = vsum + ((size_t)b * Hn + h) * Wn;
    const int* mrow = mask + ((size_t)b * Hn + h) * Wn;
    const float* p0r = pred + ((size_t)b * 2 * Hn + h) * Wn;
    const float* p1r = p0r + (size_t)Hn * Wn;

    __shared__ float P[Wn];                    // inclusive prefix of vsum row
    __shared__ float wtot[4];
    __shared__ float red[4][4];

    // ---- inclusive prefix scan of the vsum row (pair-per-thread) ----
    const float2 vv = *reinterpret_cast<const float2*>(vrow + 2 * t);
    float x = vv.x + vv.y;                     // pair sum
    const float pairSum = x;
#pragma unroll
    for (int off = 1; off < 64; off <<= 1) {
        const float n = __shfl_up(x, off, 64);
        if (lane >= off) x += n;
    }
    if (lane == 63) wtot[wv] = x;
    __syncthreads();
    float woff = 0.0f;
#pragma unroll
    for (int k = 0; k < 4; ++k) woff += (k < wv) ? wtot[k] : 0.0f;
    const float pre = woff + (x - pairSum);    // exclusive prefix of pairs
    P[2 * t] = pre + vv.x;
    P[2 * t + 1] = pre + vv.x + vv.y;
    __syncthreads();

    // ---- loss math for elements i = 2t, 2t+1 ----
    const int2 mm = *reinterpret_cast<const int2*>(mrow + 2 * t);
    const float2 q0 = *reinterpret_cast<const float2*>(p0r + 2 * t);
    const float2 q1 = *reinterpret_cast<const float2*>(p1r + 2 * t);

    float a_weit = 0.0f, a_wbce = 0.0f, a_inter = 0.0f, a_card = 0.0f;
#pragma unroll
    for (int k = 0; k < 2; ++k) {
        const int i = 2 * t + k;
        int m = k ? mm.y : mm.x;
        if (m == 255) m = 0;
        const float mf = (float)m;
        const float p0 = k ? q0.y : q0.x;
        const float p1 = k ? q1.y : q1.x;

        const int ihi = (i + PADR > Wn - 1) ? Wn - 1 : i + PADR;
        const float plo = (i >= PADR + 1) ? P[i - PADR - 1] : 0.0f;
        const float pooled = (P[ihi] - plo) * INV_KK;

        // stable 2-class log-softmax
        const float mx = fmaxf(p0, p1);
        const float lse = mx + __logf(__expf(p0 - mx) + __expf(p1 - mx));
        const float lp0 = p0 - lse;
        const float lp1 = p1 - lse;

        const float wbce = m ? -lp1 : -lp0;
        const float p1s = __expf(lp1);

        const float weit = 1.0f + 5.0f * fabsf(pooled - mf);
        a_weit += weit;
        a_wbce += weit * wbce;
        a_inter += p1s * mf * weit;
        a_card += (p1s + mf) * weit;
    }

    // ---- block reduction: 4 waves of 64 ----
#pragma unroll
    for (int off = 32; off > 0; off >>= 1) {
        a_weit += __shfl_down(a_weit, off, 64);
        a_wbce += __shfl_down(a_wbce, off, 64);
        a_inter += __shfl_down(a_inter, off, 64);
        a_card += __shfl_down(a_card, off, 64);
    }
    if (lane == 0) {
        red[wv][0] = a_weit;
        red[wv][1] = a_wbce;
        red[wv][2] = a_inter;
        red[wv][3] = a_card;
    }
    __syncthreads();
    if (t < 4) {
        part[((size_t)b * Hn + h) * 4 + t] =
            red[0][t] + red[1][t] + red[2][t] + red[3][t];
    }
}

// ------ single-block reduce of part[b][h][4] + per-batch loss + mean ------
// 1024 threads = 16 waves; wave b reduces batch b (512 rows x float4).
__global__ void __launch_bounds__(1024)
reduce_finalize_kernel(const float* __restrict__ part, float* __restrict__ out) {
    const int t = threadIdx.x;
    const int b = t >> 6;
    const int l = t & 63;

    float a0 = 0.f, a1 = 0.f, a2 = 0.f, a3 = 0.f;
    for (int h = l; h < Hn; h += 64) {
        const float4 v = *reinterpret_cast<const float4*>(part + ((size_t)b * Hn + h) * 4);
        a0 += v.x; a1 += v.y; a2 += v.z; a3 += v.w;
    }
#pragma unroll
    for (int off = 32; off > 0; off >>= 1) {
        a0 += __shfl_down(a0, off, 64);
        a1 += __shfl_down(a1, off, 64);
        a2 += __shfl_down(a2, off, 64);
        a3 += __shfl_down(a3, off, 64);
    }

    __shared__ float loss[Bn];
    if (l == 0) {
        const float wbce = a1 / a0;
        const float uni = a3 - a2;              // cardinality - inter
        const float wiou = 1.0f - (a2 + 1.0f) / (uni + 1.0f);
        loss[b] = wbce + wiou;
    }
    __syncthreads();
    if (t == 0) {
        float s = 0.0f;
#pragma unroll
        for (int k = 0; k < Bn; ++k) s += loss[k];
        out[0] = s * (1.0f / (float)Bn);
    }
}

extern "C" void kernel_launch(void* const* d_in, const int* in_sizes, int n_in,
                              void* d_out, int out_size, void* d_ws, size_t ws_size,
                              hipStream_t stream) {
    const float* pred = (const float*)d_in[0];
    const int* mask = (const int*)d_in[1];
    float* vsum = (float*)d_ws;                          // B*H*W floats = 16 MB
    float* part = vsum + (size_t)Bn * Hn * Wn;           // B*H*4 floats = 128 KB
    float* out = (float*)d_out;

    hipLaunchKernelGGL(vbox_kernel, dim3(Hn / HCH, Bn), dim3(128), 0, stream,
                       mask, vsum);
    hipLaunchKernelGGL(fused_kernel, dim3(Hn, Bn), dim3(256), 0, stream,
                       pred, mask, vsum, part);
    hipLaunchKernelGGL(reduce_finalize_kernel, dim3(1), dim3(1024), 0, stream,
                       part, out);
}

// Round 5
// 35.330 us; speedup vs baseline: 2.7296x; 1.2764x over previous
//
#include <hip/hip_runtime.h>

// Problem constants (from reference setup_inputs)
constexpr int Bn = 16;
constexpr int Hn = 512;
constexpr int Wn = 512;
constexpr int PADR = 15;              // 31x31 window, pad 15
constexpr float INV_KK = 1.0f / (31.0f * 31.0f);
constexpr int HCH = 8;                // rows per block in vbox kernel

// bank-conflict-free permutation for the prefix array (stride-4 access)
__device__ __forceinline__ int perm(int i) { return ((i & 3) << 7) | (i >> 2); }

// ---------------- pass 0: pack mask int32 -> uint8 (remap 255->0) ---------
__global__ void pack_kernel(const int* __restrict__ mask,
                            unsigned char* __restrict__ mask8) {
    const size_t i = (size_t)blockIdx.x * 256 + threadIdx.x;  // quad index
    const int4 mm = reinterpret_cast<const int4*>(mask)[i];
    uchar4 r;
    r.x = (mm.x == 255) ? 0 : (unsigned char)mm.x;
    r.y = (mm.y == 255) ? 0 : (unsigned char)mm.y;
    r.z = (mm.z == 255) ? 0 : (unsigned char)mm.z;
    r.w = (mm.w == 255) ? 0 : (unsigned char)mm.w;
    reinterpret_cast<uchar4*>(mask8)[i] = r;
}

// ---------------- pass 1: vertical 31-tap box sum, uint8 -> uint8 ---------
// grid (Hn/HCH, Bn), 128 thr; thread owns 4 adjacent columns (uchar4).
__global__ void vbox_kernel(const unsigned char* __restrict__ mask8,
                            unsigned char* __restrict__ vsum8) {
    const int h0 = blockIdx.x * HCH;
    const int b = blockIdx.y;
    const int w4 = threadIdx.x * 4;

    const unsigned char* mb = mask8 + (size_t)b * Hn * Wn;
    unsigned char* vb = vsum8 + (size_t)b * Hn * Wn;

    int s0 = 0, s1 = 0, s2 = 0, s3 = 0;
    const int lo = (h0 - PADR < 0) ? 0 : h0 - PADR;
    const int hi = (h0 + PADR > Hn - 1) ? Hn - 1 : h0 + PADR;
    for (int j = lo; j <= hi; ++j) {
        const uchar4 m = *reinterpret_cast<const uchar4*>(mb + j * Wn + w4);
        s0 += m.x; s1 += m.y; s2 += m.z; s3 += m.w;
    }

#pragma unroll
    for (int h = h0; h < h0 + HCH; ++h) {
        uchar4 o;
        o.x = (unsigned char)s0; o.y = (unsigned char)s1;
        o.z = (unsigned char)s2; o.w = (unsigned char)s3;
        *reinterpret_cast<uchar4*>(vb + h * Wn + w4) = o;
        const int ha = h + PADR + 1;
        const int hs_ = h - PADR;
        if (ha < Hn) {
            const uchar4 m = *reinterpret_cast<const uchar4*>(mb + ha * Wn + w4);
            s0 += m.x; s1 += m.y; s2 += m.z; s3 += m.w;
        }
        if (hs_ >= 0) {
            const uchar4 m = *reinterpret_cast<const uchar4*>(mb + hs_ * Wn + w4);
            s0 -= m.x; s1 -= m.y; s2 -= m.z; s3 -= m.w;
        }
    }
}

// ------- pass 2: horizontal box via row prefix scan + full loss math ------
// grid (Hn/2, Bn): block owns 2 rows. 256 thr; waves 0,1 -> row 0,
// waves 2,3 -> row 1; each thread owns 4 elems (float4 pred loads).
__global__ void fused_kernel(const float* __restrict__ pred,
                             const unsigned char* __restrict__ mask8,
                             const unsigned char* __restrict__ vsum8,
                             float* __restrict__ part) {
    const int rsel = threadIdx.x >> 7;                  // 0 or 1
    const int h = blockIdx.x * 2 + rsel;
    const int b = blockIdx.y;
    const int tl = threadIdx.x & 127;                   // thread-in-row
    const int lane = threadIdx.x & 63;
    const int wv = threadIdx.x >> 6;                    // 0..3
    const int i0 = tl * 4;

    const unsigned char* vrow = vsum8 + ((size_t)b * Hn + h) * Wn;
    const unsigned char* mrow = mask8 + ((size_t)b * Hn + h) * Wn;
    const float* p0r = pred + ((size_t)b * 2 * Hn + h) * Wn;
    const float* p1r = p0r + (size_t)Hn * Wn;

    __shared__ float P[2][Wn];                 // swizzled inclusive prefix
    __shared__ float wtot[4];
    __shared__ float red[4][4];

    // ---- inclusive prefix scan of the vsum row (quad-per-thread) ----
    const uchar4 vq = *reinterpret_cast<const uchar4*>(vrow + i0);
    const float v0 = vq.x, v1 = vq.y, v2 = vq.z, v3 = vq.w;
    float x = v0 + v1 + v2 + v3;
    const float quad = x;
#pragma unroll
    for (int off = 1; off < 64; off <<= 1) {
        const float n = __shfl_up(x, off, 64);
        if (lane >= off) x += n;
    }
    if (lane == 63) wtot[wv] = x;
    __syncthreads();
    const float woff = (wv == 1) ? wtot[0] : (wv == 3) ? wtot[2] : 0.0f;
    const float pre = woff + (x - quad);       // exclusive prefix of quads
    P[rsel][perm(i0 + 0)] = pre + v0;
    P[rsel][perm(i0 + 1)] = pre + v0 + v1;
    P[rsel][perm(i0 + 2)] = pre + v0 + v1 + v2;
    P[rsel][perm(i0 + 3)] = pre + v0 + v1 + v2 + v3;
    __syncthreads();

    // ---- loss math for elements i0..i0+3 ----
    const uchar4 mq = *reinterpret_cast<const uchar4*>(mrow + i0);
    const float4 q0 = *reinterpret_cast<const float4*>(p0r + i0);
    const float4 q1 = *reinterpret_cast<const float4*>(p1r + i0);

    float a_weit = 0.0f, a_wbce = 0.0f, a_inter = 0.0f, a_card = 0.0f;
#pragma unroll
    for (int k = 0; k < 4; ++k) {
        const int i = i0 + k;
        const int m = (k == 0) ? mq.x : (k == 1) ? mq.y : (k == 2) ? mq.z : mq.w;
        const float mf = (float)m;
        const float p0 = (k == 0) ? q0.x : (k == 1) ? q0.y : (k == 2) ? q0.z : q0.w;
        const float p1 = (k == 0) ? q1.x : (k == 1) ? q1.y : (k == 2) ? q1.z : q1.w;

        const int ihi = (i + PADR > Wn - 1) ? Wn - 1 : i + PADR;
        const float plo = (i >= PADR + 1) ? P[rsel][perm(i - PADR - 1)] : 0.0f;
        const float pooled = (P[rsel][perm(ihi)] - plo) * INV_KK;

        // stable 2-class log-softmax
        const float mx = fmaxf(p0, p1);
        const float lse = mx + __logf(__expf(p0 - mx) + __expf(p1 - mx));
        const float lp0 = p0 - lse;
        const float lp1 = p1 - lse;

        const float wbce = m ? -lp1 : -lp0;
        const float p1s = __expf(lp1);

        const float weit = 1.0f + 5.0f * fabsf(pooled - mf);
        a_weit += weit;
        a_wbce += weit * wbce;
        a_inter += p1s * mf * weit;
        a_card += (p1s + mf) * weit;
    }

    // ---- block reduction: 4 waves of 64 (rows' partials just add) ----
#pragma unroll
    for (int off = 32; off > 0; off >>= 1) {
        a_weit += __shfl_down(a_weit, off, 64);
        a_wbce += __shfl_down(a_wbce, off, 64);
        a_inter += __shfl_down(a_inter, off, 64);
        a_card += __shfl_down(a_card, off, 64);
    }
    if (lane == 0) {
        red[wv][0] = a_weit;
        red[wv][1] = a_wbce;
        red[wv][2] = a_inter;
        red[wv][3] = a_card;
    }
    __syncthreads();
    if (threadIdx.x < 4) {
        part[((size_t)b * (Hn / 2) + blockIdx.x) * 4 + threadIdx.x] =
            red[0][threadIdx.x] + red[1][threadIdx.x] +
            red[2][threadIdx.x] + red[3][threadIdx.x];
    }
}

// ------ single-block reduce of part[b][256][4] + per-batch loss + mean ----
__global__ void __launch_bounds__(1024)
reduce_finalize_kernel(const float* __restrict__ part, float* __restrict__ out) {
    const int t = threadIdx.x;
    const int b = t >> 6;
    const int l = t & 63;
    constexpr int NP = Hn / 2;                 // partials per batch

    float a0 = 0.f, a1 = 0.f, a2 = 0.f, a3 = 0.f;
    for (int j = l; j < NP; j += 64) {
        const float4 v = *reinterpret_cast<const float4*>(part + ((size_t)b * NP + j) * 4);
        a0 += v.x; a1 += v.y; a2 += v.z; a3 += v.w;
    }
#pragma unroll
    for (int off = 32; off > 0; off >>= 1) {
        a0 += __shfl_down(a0, off, 64);
        a1 += __shfl_down(a1, off, 64);
        a2 += __shfl_down(a2, off, 64);
        a3 += __shfl_down(a3, off, 64);
    }

    __shared__ float loss[Bn];
    if (l == 0) {
        const float wbce = a1 / a0;
        const float uni = a3 - a2;             // cardinality - inter
        const float wiou = 1.0f - (a2 + 1.0f) / (uni + 1.0f);
        loss[b] = wbce + wiou;
    }
    __syncthreads();
    if (t == 0) {
        float s = 0.0f;
#pragma unroll
        for (int k = 0; k < Bn; ++k) s += loss[k];
        out[0] = s * (1.0f / (float)Bn);
    }
}

extern "C" void kernel_launch(void* const* d_in, const int* in_sizes, int n_in,
                              void* d_out, int out_size, void* d_ws, size_t ws_size,
                              hipStream_t stream) {
    const float* pred = (const float*)d_in[0];
    const int* mask = (const int*)d_in[1];
    unsigned char* mask8 = (unsigned char*)d_ws;                 // 4 MB
    unsigned char* vsum8 = mask8 + (size_t)Bn * Hn * Wn;         // 4 MB
    float* part = (float*)(vsum8 + (size_t)Bn * Hn * Wn);        // 16 KB
    float* out = (float*)d_out;

    hipLaunchKernelGGL(pack_kernel, dim3(Bn * Hn * Wn / 4 / 256), dim3(256),
                       0, stream, mask, mask8);
    hipLaunchKernelGGL(vbox_kernel, dim3(Hn / HCH, Bn), dim3(128), 0, stream,
                       mask8, vsum8);
    hipLaunchKernelGGL(fused_kernel, dim3(Hn / 2, Bn), dim3(256), 0, stream,
                       pred, mask8, vsum8, part);
    hipLaunchKernelGGL(reduce_finalize_kernel, dim3(1), dim3(1024), 0, stream,
                       part, out);
}

// Round 6
// 28.467 us; speedup vs baseline: 3.3878x; 1.2411x over previous
//
#include <hip/hip_runtime.h>

// Problem constants (from reference setup_inputs)
constexpr int Bn = 16;
constexpr int Hn = 512;
constexpr int Wn = 512;
constexpr int PADR = 15;              // 31x31 window, pad 15
constexpr float INV_KK = 1.0f / (31.0f * 31.0f);
constexpr int RPW = 2;                // rows per wave (slide window once)
constexpr int WPB = 4;                // waves per block
constexpr int RPB = RPW * WPB;        // 8 rows per block
constexpr int BPB = Hn / RPB;         // 64 blocks per batch

// ---------------- pass 0: pack mask int32 -> uint8 (remap 255->0) ---------
__global__ void pack_kernel(const int* __restrict__ mask,
                            unsigned char* __restrict__ mask8) {
    const size_t i = (size_t)blockIdx.x * 256 + threadIdx.x;  // quad index
    const int4 mm = reinterpret_cast<const int4*>(mask)[i];
    uchar4 r;
    r.x = (mm.x == 255) ? 0 : (unsigned char)mm.x;
    r.y = (mm.y == 255) ? 0 : (unsigned char)mm.y;
    r.z = (mm.z == 255) ? 0 : (unsigned char)mm.z;
    r.w = (mm.w == 255) ? 0 : (unsigned char)mm.w;
    reinterpret_cast<uchar4*>(mask8)[i] = r;
}

// ------ fused: vertical box (packed-u16 regs) + in-register row scan ------
// grid (Hn/RPB, Bn), 256 thr = 4 waves; wave w owns rows h0+2w, h0+2w+1;
// lane owns 8 adjacent columns. No LDS except the final 4x4 reduction.
__global__ void fused_kernel(const float* __restrict__ pred,
                             const unsigned char* __restrict__ mask8,
                             float* __restrict__ part) {
    const int t = threadIdx.x;
    const int lane = t & 63;
    const int wv = t >> 6;
    const int b = blockIdx.y;
    const int h0 = blockIdx.x * RPB;
    const int r0 = h0 + wv * RPW;                      // first row of wave
    const int c0 = lane * 8;                           // first col of lane

    const unsigned char* mb = mask8 + (size_t)b * Hn * Wn;
    const float* pb = pred + (size_t)b * 2 * Hn * Wn;  // channel 0 base
    const float* pb1 = pb + (size_t)Hn * Wn;           // channel 1 base

    // packed u16 vertical window sums for cols c0..c0+7 (bytes<=31, no ovf)
    unsigned int e0 = 0, o0 = 0, e1 = 0, o1 = 0;
    {
        const int glo = (r0 - PADR < 0) ? 0 : r0 - PADR;
        const int ghi = (r0 + PADR > Hn - 1) ? Hn - 1 : r0 + PADR;
        for (int g = glo; g <= ghi; ++g) {
            const uint2 x = *reinterpret_cast<const uint2*>(mb + (size_t)g * Wn + c0);
            e0 += x.x & 0x00FF00FFu; o0 += (x.x >> 8) & 0x00FF00FFu;
            e1 += x.y & 0x00FF00FFu; o1 += (x.y >> 8) & 0x00FF00FFu;
        }
    }

    float a_weit = 0.f, a_wbce = 0.f, a_inter = 0.f, a_card = 0.f;

#pragma unroll
    for (int rr = 0; rr < RPW; ++rr) {
        const int r = r0 + rr;

        // ---- extract the 8 vertical sums, build in-register prefixes ----
        float q[8];
        q[0] = (float)(e0 & 0xFFFFu);
        q[1] = q[0] + (float)(o0 & 0xFFFFu);
        q[2] = q[1] + (float)(e0 >> 16);
        q[3] = q[2] + (float)(o0 >> 16);
        q[4] = q[3] + (float)(e1 & 0xFFFFu);
        q[5] = q[4] + (float)(o1 & 0xFFFFu);
        q[6] = q[5] + (float)(e1 >> 16);
        q[7] = q[6] + (float)(o1 >> 16);

        // inclusive wave scan of the lane total
        float s = q[7];
#pragma unroll
        for (int off = 1; off < 64; off <<= 1) {
            const float n = __shfl_up(s, off, 64);
            if (lane >= off) s += n;
        }
        const float pre = s - q[7];                    // exclusive prefix
        float P[8];
#pragma unroll
        for (int k = 0; k < 8; ++k) P[k] = pre + q[k];
        const float total = __shfl(P[7], 63, 64);

        // window ends via cross-lane shuffles:
        // P[i-16] lives at (lane-2, reg k); P[i+15] at (lane+1, reg 7) for
        // k==0 else (lane+2, reg k-1).
        const int sl = (lane - 2 < 0) ? 0 : lane - 2;
        const int s1 = (lane + 1 > 63) ? 63 : lane + 1;
        const int s2 = (lane + 2 > 63) ? 63 : lane + 2;
        float plo[8], phi[8];
#pragma unroll
        for (int k = 0; k < 8; ++k) plo[k] = __shfl(P[k], sl, 64);
        phi[0] = __shfl(P[7], s1, 64);
#pragma unroll
        for (int k = 1; k < 8; ++k) phi[k] = __shfl(P[k - 1], s2, 64);

        // ---- loads for this row ----
        const uint2 mm = *reinterpret_cast<const uint2*>(mb + (size_t)r * Wn + c0);
        const float4 qa0 = *reinterpret_cast<const float4*>(pb + (size_t)r * Wn + c0);
        const float4 qa1 = *reinterpret_cast<const float4*>(pb + (size_t)r * Wn + c0 + 4);
        const float4 qb0 = *reinterpret_cast<const float4*>(pb1 + (size_t)r * Wn + c0);
        const float4 qb1 = *reinterpret_cast<const float4*>(pb1 + (size_t)r * Wn + c0 + 4);
        const float pA[8] = {qa0.x, qa0.y, qa0.z, qa0.w, qa1.x, qa1.y, qa1.z, qa1.w};
        const float pB[8] = {qb0.x, qb0.y, qb0.z, qb0.w, qb1.x, qb1.y, qb1.z, qb1.w};

        // ---- loss math for the 8 owned elements ----
#pragma unroll
        for (int k = 0; k < 8; ++k) {
            const int i = c0 + k;
            const unsigned int mwrd = (k < 4) ? mm.x : mm.y;
            const int m = (mwrd >> (8 * (k & 3))) & 0xFF;
            const float mf = (float)m;
            const float p0 = pA[k];
            const float p1 = pB[k];

            const float lo_v = (i >= PADR + 1) ? plo[k] : 0.0f;
            const float hi_v = (i + PADR <= Wn - 1) ? phi[k] : total;
            const float pooled = (hi_v - lo_v) * INV_KK;

            // stable 2-class log-softmax
            const float mx = fmaxf(p0, p1);
            const float lse = mx + __logf(__expf(p0 - mx) + __expf(p1 - mx));
            const float lp0 = p0 - lse;
            const float lp1 = p1 - lse;

            const float wbce = m ? -lp1 : -lp0;
            const float p1s = __expf(lp1);

            const float weit = 1.0f + 5.0f * fabsf(pooled - mf);
            a_weit += weit;
            a_wbce += weit * wbce;
            a_inter += p1s * mf * weit;
            a_card += (p1s + mf) * weit;
        }

        // ---- slide the vertical window down one row ----
        if (rr + 1 < RPW) {
            const int ga = r + 1 + PADR;               // row entering
            const int gs = r - PADR;                   // row leaving
            if (ga < Hn) {
                const uint2 x = *reinterpret_cast<const uint2*>(mb + (size_t)ga * Wn + c0);
                e0 += x.x & 0x00FF00FFu; o0 += (x.x >> 8) & 0x00FF00FFu;
                e1 += x.y & 0x00FF00FFu; o1 += (x.y >> 8) & 0x00FF00FFu;
            }
            if (gs >= 0) {
                const uint2 x = *reinterpret_cast<const uint2*>(mb + (size_t)gs * Wn + c0);
                e0 -= x.x & 0x00FF00FFu; o0 -= (x.x >> 8) & 0x00FF00FFu;
                e1 -= x.y & 0x00FF00FFu; o1 -= (x.y >> 8) & 0x00FF00FFu;
            }
        }
    }

    // ---- block reduction: 4 waves of 64 ----
    __shared__ float red[4][4];
#pragma unroll
    for (int off = 32; off > 0; off >>= 1) {
        a_weit += __shfl_down(a_weit, off, 64);
        a_wbce += __shfl_down(a_wbce, off, 64);
        a_inter += __shfl_down(a_inter, off, 64);
        a_card += __shfl_down(a_card, off, 64);
    }
    if (lane == 0) {
        red[wv][0] = a_weit;
        red[wv][1] = a_wbce;
        red[wv][2] = a_inter;
        red[wv][3] = a_card;
    }
    __syncthreads();
    if (t < 4) {
        part[((size_t)b * BPB + blockIdx.x) * 4 + t] =
            red[0][t] + red[1][t] + red[2][t] + red[3][t];
    }
}

// ------ single-block reduce of part[b][64][4] + per-batch loss + mean -----
__global__ void __launch_bounds__(1024)
reduce_finalize_kernel(const float* __restrict__ part, float* __restrict__ out) {
    const int t = threadIdx.x;
    const int b = t >> 6;
    const int l = t & 63;

    float a0 = 0.f, a1 = 0.f, a2 = 0.f, a3 = 0.f;
    for (int j = l; j < BPB; j += 64) {
        const float4 v = *reinterpret_cast<const float4*>(part + ((size_t)b * BPB + j) * 4);
        a0 += v.x; a1 += v.y; a2 += v.z; a3 += v.w;
    }
#pragma unroll
    for (int off = 32; off > 0; off >>= 1) {
        a0 += __shfl_down(a0, off, 64);
        a1 += __shfl_down(a1, off, 64);
        a2 += __shfl_down(a2, off, 64);
        a3 += __shfl_down(a3, off, 64);
    }

    __shared__ float loss[Bn];
    if (l == 0) {
        const float wbce = a1 / a0;
        const float uni = a3 - a2;                     // cardinality - inter
        const float wiou = 1.0f - (a2 + 1.0f) / (uni + 1.0f);
        loss[b] = wbce + wiou;
    }
    __syncthreads();
    if (t == 0) {
        float s = 0.0f;
#pragma unroll
        for (int k = 0; k < Bn; ++k) s += loss[k];
        out[0] = s * (1.0f / (float)Bn);
    }
}

extern "C" void kernel_launch(void* const* d_in, const int* in_sizes, int n_in,
                              void* d_out, int out_size, void* d_ws, size_t ws_size,
                              hipStream_t stream) {
    const float* pred = (const float*)d_in[0];
    const int* mask = (const int*)d_in[1];
    unsigned char* mask8 = (unsigned char*)d_ws;                 // 4 MB
    float* part = (float*)(mask8 + (size_t)Bn * Hn * Wn);        // 16 KB
    float* out = (float*)d_out;

    hipLaunchKernelGGL(pack_kernel, dim3(Bn * Hn * Wn / 4 / 256), dim3(256),
                       0, stream, mask, mask8);
    hipLaunchKernelGGL(fused_kernel, dim3(BPB, Bn), dim3(256), 0, stream,
                       pred, mask8, part);
    hipLaunchKernelGGL(reduce_finalize_kernel, dim3(1), dim3(1024), 0, stream,
                       part, out);
}

// Round 7
// 25.935 us; speedup vs baseline: 3.7184x; 1.0976x over previous
//
#include <hip/hip_runtime.h>

// Problem constants (from reference setup_inputs)
constexpr int Bn = 16;
constexpr int Hn = 512;
constexpr int Wn = 512;
constexpr int PADR = 15;              // 31x31 window, pad 15
constexpr float INV_KK = 1.0f / (31.0f * 31.0f);

// XCD-aware flat-block decode: blocks with equal (fid%8) land on the same
// XCD (dispatch round-robins). Pin batches {2x,2x+1} to XCD x so the u8
// buffers (256 KB/batch) stay L2-resident. Bijective for grids 16*G.
__device__ __forceinline__ void decode_fid(int fid, int& b, int& grp) {
    b = (fid & 7) * 2 + ((fid >> 3) & 1);
    grp = fid >> 4;
}

// ---- pass A: pack mask -> u8 AND horizontal 31-tap box -> u8 -------------
// flat grid 1024 = 64 row-groups x 16 batches; 4 waves; wave owns 2 rows.
// Lane owns 8 cols; in-register wave scan gives the row prefix.
__global__ void pack_hbox_kernel(const int* __restrict__ mask,
                                 unsigned char* __restrict__ mask8,
                                 unsigned char* __restrict__ hsum8) {
    int b, grp;
    decode_fid(blockIdx.x, b, grp);
    const int lane = threadIdx.x & 63;
    const int wv = threadIdx.x >> 6;
    const int c0 = lane * 8;

    const int* mb = mask + (size_t)b * Hn * Wn;
    unsigned char* m8 = mask8 + (size_t)b * Hn * Wn;
    unsigned char* h8 = hsum8 + (size_t)b * Hn * Wn;

#pragma unroll
    for (int rr = 0; rr < 2; ++rr) {
        const int r = grp * 8 + wv * 2 + rr;
        const int4 a = *reinterpret_cast<const int4*>(mb + (size_t)r * Wn + c0);
        const int4 c = *reinterpret_cast<const int4*>(mb + (size_t)r * Wn + c0 + 4);
        const int mv[8] = {a.x, a.y, a.z, a.w, c.x, c.y, c.z, c.w};

        unsigned int w0 = 0, w1 = 0;
        float q[8];
        float run = 0.0f;
#pragma unroll
        for (int k = 0; k < 8; ++k) {
            const int m = (mv[k] == 255) ? 0 : mv[k];
            if (k < 4) w0 |= (unsigned int)m << (8 * k);
            else       w1 |= (unsigned int)m << (8 * (k - 4));
            run += (float)m;
            q[k] = run;                                // in-lane inclusive
        }
        *reinterpret_cast<uint2*>(m8 + (size_t)r * Wn + c0) = make_uint2(w0, w1);

        // inclusive wave scan of lane totals
        float s = q[7];
#pragma unroll
        for (int off = 1; off < 64; off <<= 1) {
            const float n = __shfl_up(s, off, 64);
            if (lane >= off) s += n;
        }
        const float pre = s - q[7];                    // exclusive prefix
        float P[8];
#pragma unroll
        for (int k = 0; k < 8; ++k) P[k] = pre + q[k];
        const float total = __shfl(P[7], 63, 64);

        // window ends: P[i-16] at (lane-2, k); P[i+15] at (lane+1, 7) for
        // k==0 else (lane+2, k-1). Clamped lanes guarded by the i-tests.
        const int sl = (lane < 2) ? 0 : lane - 2;
        const int s1 = (lane > 62) ? 63 : lane + 1;
        const int s2 = (lane > 61) ? 63 : lane + 2;
        float plo[8], phi[8];
#pragma unroll
        for (int k = 0; k < 8; ++k) plo[k] = __shfl(P[k], sl, 64);
        phi[0] = __shfl(P[7], s1, 64);
#pragma unroll
        for (int k = 1; k < 8; ++k) phi[k] = __shfl(P[k - 1], s2, 64);

        unsigned int h0w = 0, h1w = 0;
#pragma unroll
        for (int k = 0; k < 8; ++k) {
            const int i = c0 + k;
            const float lo = (i >= PADR + 1) ? plo[k] : 0.0f;
            const float hi = (i + PADR <= Wn - 1) ? phi[k] : total;
            const unsigned int hv = (unsigned int)(hi - lo);   // exact, <=31
            if (k < 4) h0w |= hv << (8 * k);
            else       h1w |= hv << (8 * (k - 4));
        }
        *reinterpret_cast<uint2*>(h8 + (size_t)r * Wn + c0) = make_uint2(h0w, h1w);
    }
}

// ---- pass B: vertical slide over hsum8 (packed u16) + loss math ----------
// flat grid 1024 = 64 row-groups x 16 batches; wave owns 2 rows; lane 8 cols.
// No shuffles, no LDS in the hot loop.
__global__ void fused_kernel(const float* __restrict__ pred,
                             const unsigned char* __restrict__ mask8,
                             const unsigned char* __restrict__ hsum8,
                             float* __restrict__ part) {
    int b, bx;
    decode_fid(blockIdx.x, b, bx);
    const int t = threadIdx.x;
    const int lane = t & 63;
    const int wv = t >> 6;
    const int r0 = bx * 8 + wv * 2;
    const int c0 = lane * 8;

    const unsigned char* hb = hsum8 + (size_t)b * Hn * Wn;
    const unsigned char* mb = mask8 + (size_t)b * Hn * Wn;
    const float* pb = pred + (size_t)b * 2 * Hn * Wn;
    const float* pb1 = pb + (size_t)Hn * Wn;

    // packed u16 vertical sums of hsum8 (<=31 each; 31 rows -> <=961, exact)
    unsigned int e0 = 0, o0 = 0, e1 = 0, o1 = 0;
    {
        const int glo = (r0 - PADR < 0) ? 0 : r0 - PADR;
        const int ghi = (r0 + PADR > Hn - 1) ? Hn - 1 : r0 + PADR;
        for (int g = glo; g <= ghi; ++g) {
            const uint2 x = *reinterpret_cast<const uint2*>(hb + (size_t)g * Wn + c0);
            e0 += x.x & 0x00FF00FFu; o0 += (x.x >> 8) & 0x00FF00FFu;
            e1 += x.y & 0x00FF00FFu; o1 += (x.y >> 8) & 0x00FF00FFu;
        }
    }

    float a_weit = 0.f, a_wbce = 0.f, a_inter = 0.f, a_card = 0.f;

#pragma unroll
    for (int rr = 0; rr < 2; ++rr) {
        const int r = r0 + rr;

        const float vs[8] = {
            (float)(e0 & 0xFFFFu), (float)(o0 & 0xFFFFu),
            (float)(e0 >> 16),     (float)(o0 >> 16),
            (float)(e1 & 0xFFFFu), (float)(o1 & 0xFFFFu),
            (float)(e1 >> 16),     (float)(o1 >> 16)};

        const uint2 mm = *reinterpret_cast<const uint2*>(mb + (size_t)r * Wn + c0);
        const float4 qa0 = *reinterpret_cast<const float4*>(pb + (size_t)r * Wn + c0);
        const float4 qa1 = *reinterpret_cast<const float4*>(pb + (size_t)r * Wn + c0 + 4);
        const float4 qb0 = *reinterpret_cast<const float4*>(pb1 + (size_t)r * Wn + c0);
        const float4 qb1 = *reinterpret_cast<const float4*>(pb1 + (size_t)r * Wn + c0 + 4);
        const float pA[8] = {qa0.x, qa0.y, qa0.z, qa0.w, qa1.x, qa1.y, qa1.z, qa1.w};
        const float pB[8] = {qb0.x, qb0.y, qb0.z, qb0.w, qb1.x, qb1.y, qb1.z, qb1.w};

#pragma unroll
        for (int k = 0; k < 8; ++k) {
            const unsigned int mwrd = (k < 4) ? mm.x : mm.y;
            const int m = (mwrd >> (8 * (k & 3))) & 0xFF;
            const float mf = (float)m;
            const float p0 = pA[k];
            const float p1 = pB[k];

            const float pooled = vs[k] * INV_KK;

            const float mx = fmaxf(p0, p1);
            const float lse = mx + __logf(__expf(p0 - mx) + __expf(p1 - mx));
            const float lp0 = p0 - lse;
            const float lp1 = p1 - lse;

            const float wbce = m ? -lp1 : -lp0;
            const float p1s = __expf(lp1);

            const float weit = 1.0f + 5.0f * fabsf(pooled - mf);
            a_weit += weit;
            a_wbce += weit * wbce;
            a_inter += p1s * mf * weit;
            a_card += (p1s + mf) * weit;
        }

        if (rr == 0) {                                 // slide window by 1 row
            const int ga = r + 1 + PADR;
            const int gs = r - PADR;
            if (ga < Hn) {
                const uint2 x = *reinterpret_cast<const uint2*>(hb + (size_t)ga * Wn + c0);
                e0 += x.x & 0x00FF00FFu; o0 += (x.x >> 8) & 0x00FF00FFu;
                e1 += x.y & 0x00FF00FFu; o1 += (x.y >> 8) & 0x00FF00FFu;
            }
            if (gs >= 0) {
                const uint2 x = *reinterpret_cast<const uint2*>(hb + (size_t)gs * Wn + c0);
                e0 -= x.x & 0x00FF00FFu; o0 -= (x.x >> 8) & 0x00FF00FFu;
                e1 -= x.y & 0x00FF00FFu; o1 -= (x.y >> 8) & 0x00FF00FFu;
            }
        }
    }

    // block reduction: 4 waves of 64
    __shared__ float red[4][4];
#pragma unroll
    for (int off = 32; off > 0; off >>= 1) {
        a_weit += __shfl_down(a_weit, off, 64);
        a_wbce += __shfl_down(a_wbce, off, 64);
        a_inter += __shfl_down(a_inter, off, 64);
        a_card += __shfl_down(a_card, off, 64);
    }
    if (lane == 0) {
        red[wv][0] = a_weit;
        red[wv][1] = a_wbce;
        red[wv][2] = a_inter;
        red[wv][3] = a_card;
    }
    __syncthreads();
    if (t < 4) {
        part[((size_t)b * 64 + bx) * 4 + t] =
            red[0][t] + red[1][t] + red[2][t] + red[3][t];
    }
}

// ------ single-block reduce of part[b][64][4] + per-batch loss + mean -----
__global__ void __launch_bounds__(1024)
reduce_finalize_kernel(const float* __restrict__ part, float* __restrict__ out) {
    const int t = threadIdx.x;
    const int b = t >> 6;
    const int l = t & 63;

    float a0 = 0.f, a1 = 0.f, a2 = 0.f, a3 = 0.f;
    for (int j = l; j < 64; j += 64) {
        const float4 v = *reinterpret_cast<const float4*>(part + ((size_t)b * 64 + j) * 4);
        a0 += v.x; a1 += v.y; a2 += v.z; a3 += v.w;
    }
#pragma unroll
    for (int off = 32; off > 0; off >>= 1) {
        a0 += __shfl_down(a0, off, 64);
        a1 += __shfl_down(a1, off, 64);
        a2 += __shfl_down(a2, off, 64);
        a3 += __shfl_down(a3, off, 64);
    }

    __shared__ float loss[Bn];
    if (l == 0) {
        const float wbce = a1 / a0;
        const float uni = a3 - a2;                     // cardinality - inter
        const float wiou = 1.0f - (a2 + 1.0f) / (uni + 1.0f);
        loss[b] = wbce + wiou;
    }
    __syncthreads();
    if (t == 0) {
        float s = 0.0f;
#pragma unroll
        for (int k = 0; k < Bn; ++k) s += loss[k];
        out[0] = s * (1.0f / (float)Bn);
    }
}

extern "C" void kernel_launch(void* const* d_in, const int* in_sizes, int n_in,
                              void* d_out, int out_size, void* d_ws, size_t ws_size,
                              hipStream_t stream) {
    const float* pred = (const float*)d_in[0];
    const int* mask = (const int*)d_in[1];
    unsigned char* mask8 = (unsigned char*)d_ws;                 // 4 MB
    unsigned char* hsum8 = mask8 + (size_t)Bn * Hn * Wn;         // 4 MB
    float* part = (float*)(hsum8 + (size_t)Bn * Hn * Wn);        // 16 KB
    float* out = (float*)d_out;

    hipLaunchKernelGGL(pack_hbox_kernel, dim3(1024), dim3(256), 0, stream,
                       mask, mask8, hsum8);
    hipLaunchKernelGGL(fused_kernel, dim3(1024), dim3(256), 0, stream,
                       pred, mask8, hsum8, part);
    hipLaunchKernelGGL(reduce_finalize_kernel, dim3(1), dim3(1024), 0, stream,
                       part, out);
}